// Round 8
// baseline (496.340 us; speedup 1.0000x reference)
//
#include <hip/hip_runtime.h>
#include <cstdint>

// Problem constants
#define D_DIM  2048
#define T_DIM  4096
#define B_DIM  2
#define M_DIM  8192   // B*T
#define DG_DIM 2048
#define N2_DIM 8192   // D*W (W=4)
#define K_DIM  2048
#define NT_TILES (K_DIM / 32)   // 64 K-tiles of 32

typedef __bf16 bf16x8 __attribute__((ext_vector_type(8)));
typedef __bf16 bf16x4 __attribute__((ext_vector_type(4)));
typedef float  f32x4  __attribute__((ext_vector_type(4)));

__device__ __forceinline__ void gload_lds16(const void* g, void* l) {
  __builtin_amdgcn_global_load_lds(
      (__attribute__((address_space(1))) void*)g,
      (__attribute__((address_space(3))) void*)l, 16, 0, 0);
}

__device__ __forceinline__ float silu_f(float a) {
  return a / (1.f + __expf(-a));
}

// ---------------------------------------------------------------------------
// Casts
// ---------------------------------------------------------------------------
__global__ void cast_f32_bf16(const float* __restrict__ src,
                              __bf16* __restrict__ dst, int n4) {
  int i = blockIdx.x * blockDim.x + threadIdx.x;
  if (i >= n4) return;
  float4 v = ((const float4*)src)[i];
  bf16x4 o;
  o[0] = (__bf16)v.x; o[1] = (__bf16)v.y; o[2] = (__bf16)v.z; o[3] = (__bf16)v.w;
  ((bf16x4*)dst)[i] = o;
}

// w2 row-permutation: GEMM column c = n0 + wn*16 + j*64 + ln holds original
// row k = 4*d + j with d = 64*(c>>8) + 16*wn + ln, so each lane's 4
// j-fragments are the 4 taps of one d.
__global__ void cast_permute_w2(const float* __restrict__ src,
                                __bf16* __restrict__ dst, int n4) {
  int i = blockIdx.x * blockDim.x + threadIdx.x;
  if (i >= n4) return;
  const int row = i >> 9;            // dest row c (512 float4 per row of 2048)
  const int pos = i & 511;
  const int blk = row >> 8;          // 256-col tile
  const int cw  = row & 255;
  const int j   = cw >> 6;           // tap
  const int wn  = (cw >> 4) & 3;
  const int ln  = cw & 15;
  const int d   = blk * 64 + wn * 16 + ln;
  const int k   = 4 * d + j;         // original w2 row
  float4 v = ((const float4*)src)[(size_t)k * 512 + pos];
  bf16x4 o;
  o[0] = (__bf16)v.x; o[1] = (__bf16)v.y; o[2] = (__bf16)v.z; o[3] = (__bf16)v.w;
  ((bf16x4*)dst)[i] = o;
}

// ---------------------------------------------------------------------------
// 256x256 tile, BK=32, 8 waves (2M x 4N interleaved).  R8 structure:
// 4 LDS buffers (4 x 16KB per matrix, 128 KiB total), stages 4 tiles ahead,
// COUNTED vmcnt(8) at body end (never a full drain in the main loop).
//
// Body X (regions: stage -> X&3, reads -> (X+1)&3):
//   M0: stage tile X+4 (4 gloads) into region X&3 (tile X's region: its
//       frags were consumed to registers, reads fenced by body X-1's barrier)
//   L0: 8 MFMA (aL,b0)      H0: 8 MFMA (aH,b0) -> b0 dies -> rd b0'(2)
//   H1: 8 MFMA (aH,b1) -> aH dies -> rd aH'(4)
//   L1: 8 MFMA (aL,b1) interleaved per-i with rd aL'[i] -> rd b1'(2)
//   end: lgkm(0); vmcnt(8); barrier
// vmcnt(8) allows stages X+3,X+4 (8 loads) to stay IN FLIGHT across the
// barrier while guaranteeing tiles <= X+2 retired (body X+1 reads X+2's
// region RAW-safely).  Steady-state: X+2's stages are ~3 bodies old ->
// the wait is a no-op.  WAR: region X&3 overwritten at M0 was last read in
// body X-1 (lgkm(0)+barrier fence).  Clamped tail stages (s>=64, k0=0) land
// in regions whose junk frag-reads are never consumed (loop ends).
// LDS swizzle (64B rows, 4 chunks): stored chunk = orig ^ ((row>>1)&3) ->
// 16-lane phases spread over 8 bank-groups x2 (2-way = free).
// NOTE (R2): natural dispatch only - XCD swizzle doubled FETCH.
// NOTE (R5): fragment live-set must stay ~one tile or it spills.
// NOTE (R7): one barrier per tile, at the END - mid-body barrier cost ~8%.
// ---------------------------------------------------------------------------

__device__ __forceinline__ void stage_unit(const __bf16* src, __bf16* sX,
                                           int s, int lq0) {
  const int k0 = (s < NT_TILES) ? (s * 32) : 0;       // clamp keeps vmcnt exact
  __bf16* dst = sX + (s & 3) * 8192;
  gload_lds16(src + k0, dst + lq0);
  gload_lds16(src + k0 + (size_t)128 * K_DIM, dst + lq0 + 4096);
}

__device__ __forceinline__ void read4(bf16x8 dst[4], const __bf16* base,
                                      const int off[4]) {
#pragma unroll
  for (int i = 0; i < 4; i++) dst[i] = *(const bf16x8*)(base + off[i]);
}

__device__ __forceinline__ void read2(bf16x8 dst[2], const __bf16* base,
                                      const int off[2]) {
#pragma unroll
  for (int j = 0; j < 2; j++) dst[j] = *(const bf16x8*)(base + off[j]);
}

__device__ __forceinline__ void mmaq8(f32x4 acc[8][4], int ib, int jb,
                                      const bf16x8 a[4], const bf16x8 b[2]) {
  __builtin_amdgcn_s_setprio(1);
#pragma unroll
  for (int i = 0; i < 4; i++)
#pragma unroll
    for (int j = 0; j < 2; j++)
      acc[ib + i][jb + j] = __builtin_amdgcn_mfma_f32_16x16x32_bf16(
          a[i], b[j], acc[ib + i][jb + j], 0, 0, 0);
  __builtin_amdgcn_s_setprio(0);
}

// One K-tile body (see header).  nxtA/nxtB = region (X+1)&3 (reads),
// stgA/stgB = region X&3 (stage target), s4 = X+4.
__device__ __forceinline__ void body_fn(f32x4 acc[8][4],
    bf16x8 aL[4], bf16x8 aH[4], bf16x8 b0[2], bf16x8 b1[2],
    const __bf16* nxtA, const __bf16* nxtB,
    __bf16* stgA, __bf16* stgB,
    const __bf16* a_src, const __bf16* b_src, int s4, int lq0,
    const int aoff[4], const int boff[2]) {
  // M0: stage tile X+4 (4 gloads, issue-only)
  {
    const int k0 = (s4 < NT_TILES) ? (s4 * 32) : 0;
    gload_lds16(a_src + k0, stgA + lq0);
    gload_lds16(a_src + k0 + (size_t)128 * K_DIM, stgA + lq0 + 4096);
    gload_lds16(b_src + k0, stgB + lq0);
    gload_lds16(b_src + k0 + (size_t)128 * K_DIM, stgB + lq0 + 4096);
  }
  __builtin_amdgcn_sched_barrier(0);
  // L0 (aL, b0)
  mmaq8(acc, 0, 0, aL, b0);
  __builtin_amdgcn_sched_barrier(0);
  // H0 (aH, b0) — b0 dies
  mmaq8(acc, 4, 0, aH, b0);
  __builtin_amdgcn_sched_barrier(0);
  read2(b0, nxtB, boff);                  // b0 <- tile X+1
  __builtin_amdgcn_sched_barrier(0);
  // H1 (aH, b1) — aH dies
  mmaq8(acc, 4, 2, aH, b1);
  __builtin_amdgcn_sched_barrier(0);
  read4(aH, nxtA + 4096, aoff);           // aH <- tile X+1 (rows +128)
  __builtin_amdgcn_sched_barrier(0);
  // L1 (aL, b1) interleaved: after group i, aL[i] dies -> reload from X+1
  __builtin_amdgcn_s_setprio(1);
#pragma unroll
  for (int i = 0; i < 4; i++) {
    acc[i][2] = __builtin_amdgcn_mfma_f32_16x16x32_bf16(aL[i], b1[0],
                                                        acc[i][2], 0, 0, 0);
    acc[i][3] = __builtin_amdgcn_mfma_f32_16x16x32_bf16(aL[i], b1[1],
                                                        acc[i][3], 0, 0, 0);
    aL[i] = *(const bf16x8*)(nxtA + aoff[i]);         // aL[i] <- tile X+1
  }
  __builtin_amdgcn_s_setprio(0);
  __builtin_amdgcn_sched_barrier(0);
  read2(b1, nxtB + 4096, boff);           // b1 <- tile X+1 (rows +128)
  // End sync: counted — stages X+3, X+4 stay in flight across the barrier.
  asm volatile("s_waitcnt lgkmcnt(0)" ::: "memory");
  asm volatile("s_waitcnt vmcnt(8)" ::: "memory");
  __builtin_amdgcn_sched_barrier(0);
  __builtin_amdgcn_s_barrier();
  __builtin_amdgcn_sched_barrier(0);
}

__device__ __forceinline__ void gemm_core(const __bf16* __restrict__ A,
                                          const __bf16* __restrict__ B,
                                          int m0, int n0,
                                          __bf16* sA, __bf16* sB,
                                          f32x4 acc[8][4]) {
  constexpr int K = K_DIM;
  const int t    = threadIdx.x;       // 0..511
  const int lane = t & 63;
  const int wv   = t >> 6;
  const int wm   = wv >> 2;           // 0..1
  const int wn   = wv & 3;            // 0..3
  const int ln   = lane & 15, qd = lane >> 4;

  // Staging: thread t handles LDS chunk q=t (row=t>>2, slot=t&3); global
  // chunk cg = (t&3) ^ ((row>>1)&3) (pre-swizzle).  h=1 half = +128 rows
  // (same swizzle since 128 ≡ 0 mod 8) handled inside stage/body.
  const __bf16 *a_src, *b_src;
  int lq0;
  {
    int q = t, row = q >> 2, cg = (q & 3) ^ ((row >> 1) & 3);
    a_src = A + (size_t)(m0 + row) * K + cg * 8;
    b_src = B + (size_t)(n0 + row) * K + cg * 8;
    lq0 = q * 8;
  }

  // Fragment LDS offsets within a region (single K-slice per tile).
  const int sw = (ln >> 1) & 3;
  int aoff[4], boff[2];
#pragma unroll
  for (int i = 0; i < 4; i++)
    aoff[i] = (wm * 16 + i * 32 + ln) * 32 + ((qd ^ sw) << 3);
#pragma unroll
  for (int j = 0; j < 2; j++)
    boff[j] = (wn * 16 + j * 64 + ln) * 32 + ((qd ^ sw) << 3);

  __bf16* A0 = sA;              __bf16* A1 = sA + 8192;
  __bf16* A2 = sA + 16384;      __bf16* A3 = sA + 24576;
  __bf16* B0 = sB;              __bf16* B1 = sB + 8192;
  __bf16* B2 = sB + 16384;      __bf16* B3 = sB + 24576;

  bf16x8 aL[4], aH[4], b0[2], b1[2];

  // Prologue: stage tiles 0..3 (16 loads); retire tile0; read frags(0);
  // retire tile1; publish.  Entering body 0: frags(0) in regs, tiles<=1
  // retired, stages 2,3 in flight — the steady-state invariant.
  stage_unit(a_src, sA, 0, lq0);
  stage_unit(b_src, sB, 0, lq0);
  stage_unit(a_src, sA, 1, lq0);
  stage_unit(b_src, sB, 1, lq0);
  stage_unit(a_src, sA, 2, lq0);
  stage_unit(b_src, sB, 2, lq0);
  stage_unit(a_src, sA, 3, lq0);
  stage_unit(b_src, sB, 3, lq0);
  asm volatile("s_waitcnt vmcnt(12)" ::: "memory");   // tile0 landed
  __builtin_amdgcn_s_barrier();
  __builtin_amdgcn_sched_barrier(0);
  read4(aL, A0, aoff);
  read4(aH, A0 + 4096, aoff);
  read2(b0, B0, boff);
  read2(b1, B0 + 4096, boff);
  asm volatile("s_waitcnt lgkmcnt(0)" ::: "memory");
  asm volatile("s_waitcnt vmcnt(8)" ::: "memory");    // tile1 landed
  __builtin_amdgcn_sched_barrier(0);
  __builtin_amdgcn_s_barrier();
  __builtin_amdgcn_sched_barrier(0);

  for (int it = 0; it < NT_TILES / 4; ++it) {
    const int X = 4 * it;
    body_fn(acc, aL, aH, b0, b1, A1, B1, A0, B0, a_src, b_src, X + 4, lq0,
            aoff, boff);
    body_fn(acc, aL, aH, b0, b1, A2, B2, A1, B1, a_src, b_src, X + 5, lq0,
            aoff, boff);
    body_fn(acc, aL, aH, b0, b1, A3, B3, A2, B2, a_src, b_src, X + 6, lq0,
            aoff, boff);
    body_fn(acc, aL, aH, b0, b1, A0, B0, A3, B3, a_src, b_src, X + 7, lq0,
            aoff, boff);
  }
  // Drain clamped tail staging before LDS is reused/deallocated.
  asm volatile("s_waitcnt vmcnt(0)" ::: "memory");
}

// ---------------------------------------------------------------------------
// GEMM1: H = silu(x_bf16 @ w1_bf16^T).  Natural dispatch (column-per-XCD).
// ---------------------------------------------------------------------------
__global__ __launch_bounds__(512) void gemm1_silu(
    const __bf16* __restrict__ A, const __bf16* __restrict__ B,
    __bf16* __restrict__ H) {
  __shared__ __bf16 sA[4 * 8192];
  __shared__ __bf16 sB[4 * 8192];
  const int m0 = blockIdx.y * 256, n0 = blockIdx.x * 256;
  f32x4 acc[8][4] = {};
  gemm_core(A, B, m0, n0, sA, sB, acc);

  const int lane = threadIdx.x & 63;
  const int wv   = threadIdx.x >> 6;
  const int wm   = wv >> 2, wn = wv & 3;
  const int ln   = lane & 15, qd = lane >> 4;
#pragma unroll
  for (int i = 0; i < 8; i++) {
    const int row0 = m0 + wm * 16 + i * 32 + qd * 4;
#pragma unroll
    for (int j = 0; j < 4; j++) {
      const int col = n0 + wn * 16 + j * 64 + ln;
#pragma unroll
      for (int r = 0; r < 4; r++)
        H[(size_t)(row0 + r) * DG_DIM + col] = (__bf16)silu_f(acc[i][j][r]);
    }
  }
}

// ---------------------------------------------------------------------------
// GEMM2 + fused causal depthwise conv + silu.  B = permuted w2; lane owns
// d = (n0>>2) + wn*16 + ln; its 4 j-fragments are taps w=0..3 of that d.
// Natural dispatch (R2 lesson).
// ---------------------------------------------------------------------------
__global__ __launch_bounds__(512) void gemm2_conv_silu(
    const __bf16* __restrict__ A, const __bf16* __restrict__ B,
    const float* __restrict__ b2, const float* __restrict__ x,
    float* __restrict__ out) {
  __shared__ __bf16 sA[4 * 8192];
  __shared__ __bf16 sB[4 * 8192];
  const int m0 = blockIdx.y * 256, n0 = blockIdx.x * 256;
  f32x4 acc[8][4] = {};
  gemm_core(A, B, m0, n0, sA, sB, acc);

  const int lane = threadIdx.x & 63;
  const int wv   = threadIdx.x >> 6;
  const int wm   = wv >> 2, wn = wv & 3;
  const int ln   = lane & 15, qd = lane >> 4;

  const int d = (n0 >> 2) + wn * 16 + ln;
  const float4 bias = *(const float4*)(b2 + 4 * d);

#pragma unroll
  for (int i = 0; i < 8; i++) {
    const int m_base = m0 + wm * 16 + i * 32 + qd * 4;   // + r
    const int b  = m_base >> 12;                          // T=4096
    const int tb = m_base & 4095;
    // taps: x[b, tb + s - 3, d] for s = r + j in [0,6]
    float xv[7];
#pragma unroll
    for (int s = 0; s < 7; s++) {
      const int tp = tb + s - 3;
      xv[s] = (tp >= 0) ? x[((size_t)((b << 12) + tp)) * D_DIM + d] : 0.f;
    }
#pragma unroll
    for (int r = 0; r < 4; r++) {
      float y = (acc[i][0][r] + bias.x) * xv[r + 0]
              + (acc[i][1][r] + bias.y) * xv[r + 1]
              + (acc[i][2][r] + bias.z) * xv[r + 2]
              + (acc[i][3][r] + bias.w) * xv[r + 3];
      out[(size_t)(m_base + r) * D_DIM + d] = silu_f(y);
    }
  }
}

extern "C" void kernel_launch(void* const* d_in, const int* in_sizes, int n_in,
                              void* d_out, int out_size, void* d_ws, size_t ws_size,
                              hipStream_t stream) {
  (void)in_sizes; (void)n_in; (void)out_size; (void)ws_size;
  const float* x  = (const float*)d_in[0];
  const float* w1 = (const float*)d_in[1];
  const float* w2 = (const float*)d_in[2];
  const float* b2 = (const float*)d_in[3];
  float* out = (float*)d_out;

  __bf16* xb  = (__bf16*)d_ws;                        // 8192*2048
  __bf16* w1b = xb  + (size_t)M_DIM * D_DIM;          // 2048*2048
  __bf16* w2b = w1b + (size_t)DG_DIM * D_DIM;         // 8192*2048 (permuted)
  __bf16* hb  = w2b + (size_t)N2_DIM * DG_DIM;        // 8192*2048

  {
    int n4 = M_DIM * D_DIM / 4;
    cast_f32_bf16<<<(n4 + 255) / 256, 256, 0, stream>>>(x, xb, n4);
  }
  {
    int n4 = DG_DIM * D_DIM / 4;
    cast_f32_bf16<<<(n4 + 255) / 256, 256, 0, stream>>>(w1, w1b, n4);
  }
  {
    int n4 = N2_DIM * DG_DIM / 4;
    cast_permute_w2<<<(n4 + 255) / 256, 256, 0, stream>>>(w2, w2b, n4);
  }

  gemm1_silu<<<dim3(DG_DIM / 256, M_DIM / 256), 512, 0, stream>>>(xb, w1b, hb);
  gemm2_conv_silu<<<dim3(N2_DIM / 256, M_DIM / 256), 512, 0, stream>>>(
      hb, w2b, b2, x, out);
}